// Round 3
// baseline (389.585 us; speedup 1.0000x reference)
//
#include <hip/hip_runtime.h>
#include <hip/hip_bf16.h>

#define BB 2
#define CIN 64
#define COUT 64
#define KK 9
#define WW 192
#define HH 192
#define CENTER 4
#define HT 32
#define GROUPS 16
constexpr float EPSV = 1e-5f;
constexpr int NPERG = 4 * WW * HH; // elements per GN group

__device__ __forceinline__ float bf2f(unsigned short u) {
    union { unsigned int i; float f; } x; x.i = ((unsigned int)u) << 16; return x.f;
}
__device__ __forceinline__ unsigned short f2bf(float f) {
    union { float f; unsigned int i; } x; x.f = f;
    unsigned int i = x.i;
    unsigned int r = i + 0x7FFFu + ((i >> 16) & 1u);
    return (unsigned short)(r >> 16);
}

// K1: offset conv (first 9 channels only) + bias + bn + tanh + snake-cumsum.
// Thread per (b,w,h). Writes y_cum[b][k][w][h].
__global__ __launch_bounds__(256) void k_offset(
    const float* __restrict__ f, const float* __restrict__ ow,
    const float* __restrict__ ob, const float* __restrict__ bg,
    const float* __restrict__ bb, float* __restrict__ ycum)
{
    int g = blockIdx.x * 256 + threadIdx.x;
    if (g >= BB * WW * HH) return;
    int h = g % HH;
    int w = (g / HH) % WW;
    int b = g / (WW * HH);

    float acc[KK];
#pragma unroll
    for (int j = 0; j < KK; ++j) acc[j] = 0.f;

    const float* fb = f + (size_t)b * CIN * WW * HH;
#pragma unroll
    for (int dw = 0; dw < 3; ++dw) {
        int r = w + dw - 1;
        if (r < 0 || r >= WW) continue;
#pragma unroll
        for (int dh = 0; dh < 3; ++dh) {
            int cl = h + dh - 1;
            if (cl < 0 || cl >= HH) continue;
            const float* fp = fb + r * HH + cl;
            const float* wp = ow + dw * 3 + dh;
            for (int c = 0; c < CIN; ++c) {
                float v = fp[c * WW * HH];
#pragma unroll
                for (int j = 0; j < KK; ++j)
                    acc[j] += v * wp[j * (CIN * 9) + c * 9];
            }
        }
    }
    const float inv = 1.0f / sqrtf(1.0f + EPSV);
    float t[KK];
#pragma unroll
    for (int j = 0; j < KK; ++j)
        t[j] = tanhf((acc[j] + ob[j]) * inv * bg[j] + bb[j]);

    // cumsum quirk: indices 0 and 8 stay raw (loop is range(1, center))
    float cum[KK];
    cum[CENTER] = 0.f;
    cum[5] = t[5];            cum[6] = cum[5] + t[6];  cum[7] = cum[6] + t[7];
    cum[3] = t[3];            cum[2] = cum[3] + t[2];  cum[1] = cum[2] + t[1];
    cum[0] = t[0];            cum[8] = t[8];

#pragma unroll
    for (int j = 0; j < KK; ++j)
        ycum[((b * KK + j) * WW + w) * HH + h] = cum[j];
}

// K2: transpose conv weights to wt[ck][o]  (ck = c*9+k)
__global__ void k_wt(const float* __restrict__ cw, float* __restrict__ wt)
{
    int i = blockIdx.x * 256 + threadIdx.x;
    if (i >= COUT * CIN * KK) return;
    int o = i / (CIN * KK);
    int ck = i % (CIN * KK);
    wt[ck * COUT + o] = cw[i];
}

// K3: sample deformed tile (bf16 in LDS) + stride-K conv + GN partial stats.
// Block = (h-tile of 32, w, b). 256 threads. Samples always from batch 0 (ref quirk).
__global__ __launch_bounds__(256) void k_main(
    const float* __restrict__ f, const float* __restrict__ ycum,
    const float* __restrict__ wt, const float* __restrict__ cb,
    float* __restrict__ zout, float* __restrict__ stats)
{
    __shared__ unsigned short def[CIN * KK * HT]; // [c][k][h] bf16  (36 KB)
    __shared__ short m_y0[KK * HT], m_y1[KK * HT], m_x[KK * HT];
    __shared__ float m_w0[KK * HT], m_w1[KK * HT];
    __shared__ float sgrp[GROUPS], ssq[GROUPS];

    int tid = threadIdx.x;
    int h0blk = blockIdx.x * HT;
    int w = blockIdx.y;
    int b = blockIdx.z;

    // meta: per (k, h) sampling coords/weights
    for (int p = tid; p < KK * HT; p += 256) {
        int k = p / HT;
        int hl = p % HT;
        int h = h0blk + hl;
        float yf = ycum[((b * KK + k) * WW + w) * HH + h] + (float)w;
        int x = h + k - CENTER;
        float y0f = floorf(yf);
        int iy0 = (int)y0f;
        int y0i = min(max(iy0, 0), WW - 1);
        int y1i = min(max(iy0 + 1, 0), WW - 1);
        float y0w = fminf(fmaxf(y0f, 0.f), (float)WW);
        float y1w = fminf(fmaxf(y0f + 1.f, 0.f), (float)WW);
        float w0 = y1w - yf;
        float w1 = yf - y0w;
        if (x < 0 || x >= HH) { w0 = 0.f; w1 = 0.f; }
        m_y0[p] = (short)y0i;
        m_y1[p] = (short)y1i;
        m_x[p]  = (short)min(max(x, 0), HH - 1);
        m_w0[p] = w0;
        m_w1[p] = w1;
    }
    if (tid < GROUPS) { sgrp[tid] = 0.f; ssq[tid] = 0.f; }
    __syncthreads();

    // stage deformed values (always from f[0] — reference quirk)
    {
        int hl = tid % HT;
        int cg = tid / HT; // 0..7
        for (int k = 0; k < KK; ++k) {
            int p = k * HT + hl;
            int y0i = m_y0[p], y1i = m_y1[p], x = m_x[p];
            float w0 = m_w0[p], w1 = m_w1[p];
            const float* p0 = f + y0i * HH + x;
            const float* p1 = f + y1i * HH + x;
#pragma unroll
            for (int cc = 0; cc < CIN / 8; ++cc) {
                int c = cg * (CIN / 8) + cc;
                float v = p0[c * WW * HH] * w0 + p1[c * WW * HH] * w1;
                def[(c * KK + k) * HT + hl] = f2bf(v);
            }
        }
    }
    __syncthreads();

    // conv: each thread 4 o × 2 h
    int hg = tid % 16;
    int og = tid / 16;     // == GN group of its 4 channels
    int hh0 = hg * 2;
    float a00 = 0.f, a01 = 0.f, a10 = 0.f, a11 = 0.f;
    float a20 = 0.f, a21 = 0.f, a30 = 0.f, a31 = 0.f;
    const float4* wt4 = (const float4*)wt;
    for (int ck = 0; ck < CIN * KK; ++ck) {
        unsigned int v2 = *(const unsigned int*)&def[ck * HT + hh0];
        float v0 = bf2f((unsigned short)(v2 & 0xffffu));
        float v1 = bf2f((unsigned short)(v2 >> 16));
        float4 wv = wt4[ck * (COUT / 4) + og];
        a00 += wv.x * v0; a01 += wv.x * v1;
        a10 += wv.y * v0; a11 += wv.y * v1;
        a20 += wv.z * v0; a21 += wv.z * v1;
        a30 += wv.w * v0; a31 += wv.w * v1;
    }

    float lsum = 0.f, lsq = 0.f;
    float accs[4][2] = {{a00,a01},{a10,a11},{a20,a21},{a30,a31}};
#pragma unroll
    for (int i = 0; i < 4; ++i) {
        int o = og * 4 + i;
        float bias = cb[o];
        float z0 = accs[i][0] + bias;
        float z1 = accs[i][1] + bias;
        size_t base = (((size_t)b * COUT + o) * WW + w) * HH + h0blk + hh0;
        *(float2*)&zout[base] = make_float2(z0, z1);
        lsum += z0 + z1;
        lsq  += z0 * z0 + z1 * z1;
    }
    // reduce across the 16 threads sharing og (consecutive tids)
#pragma unroll
    for (int m = 1; m < 16; m <<= 1) {
        lsum += __shfl_xor(lsum, m);
        lsq  += __shfl_xor(lsq, m);
    }
    if ((tid & 15) == 0) {
        atomicAdd(&sgrp[og], lsum);
        atomicAdd(&ssq[og], lsq);
    }
    __syncthreads();
    if (tid < GROUPS) {
        atomicAdd(&stats[b * GROUPS + tid], sgrp[tid]);
        atomicAdd(&stats[BB * GROUPS + b * GROUPS + tid], ssq[tid]);
    }
}

// K4: finalize GN stats
__global__ void k_stats(const float* __restrict__ stats, float* __restrict__ ms)
{
    int i = threadIdx.x;
    if (i >= BB * GROUPS) return;
    float s = stats[i];
    float q = stats[BB * GROUPS + i];
    float mean = s / (float)NPERG;
    float var = q / (float)NPERG - mean * mean;
    ms[i] = mean;
    ms[BB * GROUPS + i] = 1.0f / sqrtf(var + EPSV);
}

// K5: normalize + affine + relu, in place on d_out
__global__ __launch_bounds__(256) void k_norm(
    float* __restrict__ z, const float* __restrict__ ms,
    const float* __restrict__ gg, const float* __restrict__ gb)
{
    int i = blockIdx.x * 256 + threadIdx.x;
    const int total4 = BB * COUT * WW * HH / 4;
    if (i >= total4) return;
    float4 v = ((float4*)z)[i];
    int idx = i * 4;
    int o = (idx / (WW * HH)) % COUT;
    int b = idx / (COUT * WW * HH);
    int g = o >> 2;
    float mean = ms[b * GROUPS + g];
    float istd = ms[BB * GROUPS + b * GROUPS + g];
    float ga = gg[o], be = gb[o];
    v.x = fmaxf((v.x - mean) * istd * ga + be, 0.f);
    v.y = fmaxf((v.y - mean) * istd * ga + be, 0.f);
    v.z = fmaxf((v.z - mean) * istd * ga + be, 0.f);
    v.w = fmaxf((v.w - mean) * istd * ga + be, 0.f);
    ((float4*)z)[i] = v;
}

extern "C" void kernel_launch(void* const* d_in, const int* in_sizes, int n_in,
                              void* d_out, int out_size, void* d_ws, size_t ws_size,
                              hipStream_t stream)
{
    const float* f  = (const float*)d_in[0];
    const float* ow = (const float*)d_in[1];
    const float* ob = (const float*)d_in[2];
    const float* bg = (const float*)d_in[3];
    const float* bb = (const float*)d_in[4];
    const float* cw = (const float*)d_in[5];
    const float* cb = (const float*)d_in[6];
    const float* gg = (const float*)d_in[7];
    const float* gb = (const float*)d_in[8];
    float* out = (float*)d_out;

    char* ws = (char*)d_ws;
    float* ycum  = (float*)ws;                       // B*9*W*H*4 = 2,654,208 B
    float* wt    = (float*)(ws + 2654208);           // 576*64*4 = 147,456 B
    float* stats = (float*)(ws + 2654208 + 147456);  // 64 floats (sum, sumsq)
    float* ms    = stats + 64;                       // 64 floats (mean, istd)

    hipMemsetAsync(stats, 0, 64 * sizeof(float), stream);
    k_offset<<<(BB * WW * HH + 255) / 256, 256, 0, stream>>>(f, ow, ob, bg, bb, ycum);
    k_wt<<<(COUT * CIN * KK + 255) / 256, 256, 0, stream>>>(cw, wt);
    k_main<<<dim3(HH / HT, WW, BB), 256, 0, stream>>>(f, ycum, wt, cb, out, stats);
    k_stats<<<1, 64, 0, stream>>>(stats, ms);
    k_norm<<<(BB * COUT * WW * HH / 4 + 255) / 256, 256, 0, stream>>>(out, ms, gg, gb);
}

// Round 4
// 338.626 us; speedup vs baseline: 1.1505x; 1.1505x over previous
//
#include <hip/hip_runtime.h>

#define BB 2
#define CIN 64
#define COUT 64
#define KK 9
#define WW 192
#define HH 192
#define WH (WW*HH)
#define CENTER 4
#define NT 32
#define DEFP 584      // padded LDS row length (ck dim), 1168 B rows
#define GROUPS 16
constexpr float EPSV = 1e-5f;
constexpr int NPERG = 4 * WW * HH;

typedef __attribute__((ext_vector_type(8))) short short8v;
typedef __attribute__((ext_vector_type(4))) float float4v;

__device__ __forceinline__ unsigned short f2bf(float f) {
    union { float f; unsigned int i; } x; x.f = f;
    unsigned int i = x.i;
    unsigned int r = i + 0x7FFFu + ((i >> 16) & 1u);
    return (unsigned short)(r >> 16);
}

// K0: weight prep. wtA[o][k*64+c] (bf16) for the MFMA conv;
//     wl_g[c][tap][12] (fp32, padded) for the offset conv.
__global__ void k_prep(const float* __restrict__ cw, const float* __restrict__ ow,
                       unsigned short* __restrict__ wtA, float* __restrict__ wl_g)
{
    int i = blockIdx.x * 256 + threadIdx.x;
    if (i < COUT * CIN * KK) {
        int o = i / 576, ck = i % 576;
        int k = ck >> 6, c = ck & 63;
        wtA[i] = f2bf(cw[o * 576 + c * 9 + k]);
    }
    int j2 = i - COUT * CIN * KK;
    if (j2 >= 0 && j2 < CIN * 9 * 12) {
        int c = j2 / 108, rem = j2 % 108, tap = rem / 12, jj = rem % 12;
        wl_g[j2] = (jj < 9) ? ow[jj * 576 + c * 9 + tap] : 0.f;
    }
}

// K1: offset conv + bias + bn + tanh + snake-cumsum.
// Block 256 = 64 h x 4 c-chunks; grid (3, W, B).
__global__ __launch_bounds__(256) void k_offset(
    const float* __restrict__ f, const float* __restrict__ wl_g,
    const float* __restrict__ ob, const float* __restrict__ bg,
    const float* __restrict__ bb, float* __restrict__ ycum)
{
    __shared__ float4 wl4[1728];      // [c][tap][12] = 27.6 KB
    __shared__ float sacc[64 * 37];   // padded, 9.5 KB
    float* wl = (float*)wl4;

    int tid = threadIdx.x;
    for (int i = tid; i < 1728; i += 256)
        wl4[i] = ((const float4*)wl_g)[i];

    int hl = tid & 63, ch = tid >> 6;
    int h = blockIdx.x * 64 + hl;
    int w = blockIdx.y, b = blockIdx.z;
    __syncthreads();

    float acc[9];
#pragma unroll
    for (int j = 0; j < 9; ++j) acc[j] = 0.f;

    const float* fb = f + ((size_t)b * CIN + ch * 16) * WH;
    for (int ci = 0; ci < 16; ++ci) {
        const float* fc = fb + ci * WH;
        const float* wp = wl + (ch * 16 + ci) * 108;
#pragma unroll
        for (int dw = 0; dw < 3; ++dw) {
            int r = w + dw - 1;
            if ((unsigned)r >= WW) continue;
            const float* fr_ = fc + r * HH;
#pragma unroll
            for (int dh = 0; dh < 3; ++dh) {
                int cl = h + dh - 1;
                if ((unsigned)cl >= HH) continue;
                float v = fr_[cl];
                const float* ww = wp + (dw * 3 + dh) * 12;
                float4 wa = *(const float4*)ww;
                float4 wb2 = *(const float4*)(ww + 4);
                float w8 = ww[8];
                acc[0] += v * wa.x;  acc[1] += v * wa.y;
                acc[2] += v * wa.z;  acc[3] += v * wa.w;
                acc[4] += v * wb2.x; acc[5] += v * wb2.y;
                acc[6] += v * wb2.z; acc[7] += v * wb2.w;
                acc[8] += v * w8;
            }
        }
    }
#pragma unroll
    for (int j = 0; j < 9; ++j)
        sacc[hl * 37 + ch * 9 + j] = acc[j];
    __syncthreads();

    if (tid < 64) {
        float s[9];
#pragma unroll
        for (int j = 0; j < 9; ++j)
            s[j] = sacc[tid * 37 + j] + sacc[tid * 37 + 9 + j] +
                   sacc[tid * 37 + 18 + j] + sacc[tid * 37 + 27 + j];
        const float inv = 1.0f / sqrtf(1.0f + EPSV);
        float t[9];
#pragma unroll
        for (int j = 0; j < 9; ++j)
            t[j] = tanhf((s[j] + ob[j]) * inv * bg[j] + bb[j]);
        // cumsum quirk: indices 0 and 8 stay raw (loop is range(1, center))
        float cum[9];
        cum[4] = 0.f;
        cum[5] = t[5]; cum[6] = cum[5] + t[6]; cum[7] = cum[6] + t[7];
        cum[3] = t[3]; cum[2] = cum[3] + t[2]; cum[1] = cum[2] + t[1];
        cum[0] = t[0]; cum[8] = t[8];
        int hh = blockIdx.x * 64 + tid;
#pragma unroll
        for (int j = 0; j < 9; ++j)
            ycum[((b * KK + j) * WW + w) * HH + hh] = cum[j];
    }
}

// K2: sample deformed tile (bf16 LDS) + MFMA conv + GN partial stats.
// Block 256 (4 waves); grid (H/NT, W, B). Samples always from f[0] (ref quirk).
__global__ __launch_bounds__(256) void k_main(
    const float* __restrict__ f, const float* __restrict__ ycum,
    const unsigned short* __restrict__ wtA, const float* __restrict__ cb,
    float* __restrict__ zout, float* __restrict__ stats)
{
    __shared__ unsigned short def[NT * DEFP];   // [h][ck2], 37.4 KB
    __shared__ short m_y0[KK * NT], m_y1[KK * NT], m_x[KK * NT];
    __shared__ float m_w0[KK * NT], m_w1[KK * NT];

    int tid = threadIdx.x;
    int h0blk = blockIdx.x * NT;
    int w = blockIdx.y;
    int b = blockIdx.z;
    int lane = tid & 63;
    int wid = tid >> 6;
    int lr = lane & 15;
    int lg = lane >> 4;
    int o0 = wid * 16;

    // A-fragments: weights for this wave's 16 output channels (18 K-steps)
    short8v afr[18];
    const unsigned short* wbase = wtA + (o0 + lr) * 576 + lg * 8;
#pragma unroll
    for (int s = 0; s < 18; ++s)
        afr[s] = *(const short8v*)(wbase + s * 32);

    // meta: per (k,h) sampling rows/weights
    for (int p = tid; p < KK * NT; p += 256) {
        int k = p / NT;
        int hl = p % NT;
        int h = h0blk + hl;
        float yf = ycum[((b * KK + k) * WW + w) * HH + h] + (float)w;
        int x = h + k - CENTER;
        float y0f = floorf(yf);
        int iy0 = (int)y0f;
        int y0i = min(max(iy0, 0), WW - 1);
        int y1i = min(max(iy0 + 1, 0), WW - 1);
        float y0w = fminf(fmaxf(y0f, 0.f), (float)WW);
        float y1w = fminf(fmaxf(y0f + 1.f, 0.f), (float)WW);
        float w0 = y1w - yf;
        float w1 = yf - y0w;
        if (x < 0 || x >= HH) { w0 = 0.f; w1 = 0.f; }
        m_y0[p] = (short)y0i;
        m_y1[p] = (short)y1i;
        m_x[p]  = (short)min(max(x, 0), HH - 1);
        m_w0[p] = w0;
        m_w1[p] = w1;
    }
    __syncthreads();

    // stage def[h][k*64+c] (bf16), sampling from f[0]
    {
        int hl = tid & 31;
        int cg = tid >> 5;   // 0..7
        for (int k = 0; k < KK; ++k) {
            int p = k * NT + hl;
            int y0i = m_y0[p], y1i = m_y1[p], x = m_x[p];
            float w0 = m_w0[p], w1 = m_w1[p];
            const float* p0 = f + y0i * HH + x;
            const float* p1 = f + y1i * HH + x;
            short8v pv;
#pragma unroll
            for (int cc = 0; cc < 8; ++cc) {
                int c = cg * 8 + cc;
                float v = p0[c * WH] * w0 + p1[c * WH] * w1;
                pv[cc] = (short)f2bf(v);
            }
            *(short8v*)&def[hl * DEFP + k * 64 + cg * 8] = pv;
        }
    }
    __syncthreads();

    // MFMA: C[16o x 32h] per wave, K=576 in 18 steps
    float4v acc0 = {0.f, 0.f, 0.f, 0.f};
    float4v acc1 = {0.f, 0.f, 0.f, 0.f};
    const unsigned short* drow0 = &def[lr * DEFP + lg * 8];
    const unsigned short* drow1 = &def[(16 + lr) * DEFP + lg * 8];
#pragma unroll
    for (int s = 0; s < 18; ++s) {
        short8v b0 = *(const short8v*)(drow0 + s * 32);
        short8v b1 = *(const short8v*)(drow1 + s * 32);
        acc0 = __builtin_amdgcn_mfma_f32_16x16x32_bf16(afr[s], b0, acc0, 0, 0, 0);
        acc1 = __builtin_amdgcn_mfma_f32_16x16x32_bf16(afr[s], b1, acc1, 0, 0, 0);
    }

    // epilogue: bias, store z, GN partial stats
    float4 cbv = *(const float4*)(cb + o0 + lg * 4);
    float lsum = 0.f, lsq = 0.f;
    size_t base = ((size_t)(b * COUT + o0 + lg * 4) * WW + w) * HH + h0blk + lr;
#pragma unroll
    for (int r = 0; r < 4; ++r) {
        float bias = (r == 0) ? cbv.x : (r == 1) ? cbv.y : (r == 2) ? cbv.z : cbv.w;
        float z0 = acc0[r] + bias;
        float z1 = acc1[r] + bias;
        zout[base + (size_t)r * WH]      = z0;
        zout[base + (size_t)r * WH + 16] = z1;
        lsum += z0 + z1;
        lsq  += z0 * z0 + z1 * z1;
    }
#pragma unroll
    for (int m = 1; m < 16; m <<= 1) {
        lsum += __shfl_xor(lsum, m);
        lsq  += __shfl_xor(lsq, m);
    }
    if (lr == 0) {
        int g = wid * 4 + lg;
        atomicAdd(&stats[b * GROUPS + g], lsum);
        atomicAdd(&stats[BB * GROUPS + b * GROUPS + g], lsq);
    }
}

// K3: finalize GN stats
__global__ void k_stats(const float* __restrict__ stats, float* __restrict__ ms)
{
    int i = threadIdx.x;
    if (i >= BB * GROUPS) return;
    float s = stats[i];
    float q = stats[BB * GROUPS + i];
    float mean = s / (float)NPERG;
    float var = q / (float)NPERG - mean * mean;
    ms[i] = mean;
    ms[BB * GROUPS + i] = 1.0f / sqrtf(var + EPSV);
}

// K4: normalize + affine + relu, in place on d_out
__global__ __launch_bounds__(256) void k_norm(
    float* __restrict__ z, const float* __restrict__ ms,
    const float* __restrict__ gg, const float* __restrict__ gb)
{
    int i = blockIdx.x * 256 + threadIdx.x;
    const int total4 = BB * COUT * WW * HH / 4;
    if (i >= total4) return;
    float4 v = ((float4*)z)[i];
    int idx = i * 4;
    int o = (idx / WH) % COUT;
    int b = idx / (COUT * WH);
    int g = o >> 2;
    float mean = ms[b * GROUPS + g];
    float istd = ms[BB * GROUPS + b * GROUPS + g];
    float ga = gg[o], be = gb[o];
    v.x = fmaxf((v.x - mean) * istd * ga + be, 0.f);
    v.y = fmaxf((v.y - mean) * istd * ga + be, 0.f);
    v.z = fmaxf((v.z - mean) * istd * ga + be, 0.f);
    v.w = fmaxf((v.w - mean) * istd * ga + be, 0.f);
    ((float4*)z)[i] = v;
}

extern "C" void kernel_launch(void* const* d_in, const int* in_sizes, int n_in,
                              void* d_out, int out_size, void* d_ws, size_t ws_size,
                              hipStream_t stream)
{
    const float* f  = (const float*)d_in[0];
    const float* ow = (const float*)d_in[1];
    const float* ob = (const float*)d_in[2];
    const float* bg = (const float*)d_in[3];
    const float* bb = (const float*)d_in[4];
    const float* cw = (const float*)d_in[5];
    const float* cb = (const float*)d_in[6];
    const float* gg = (const float*)d_in[7];
    const float* gb = (const float*)d_in[8];
    float* out = (float*)d_out;

    char* ws = (char*)d_ws;
    float* ycum          = (float*)ws;                              // 2,654,208 B
    unsigned short* wtA  = (unsigned short*)(ws + 2654208);         // 73,728 B
    float* wl_g          = (float*)(ws + 2654208 + 73728);          // 27,648 B
    float* stats         = (float*)(ws + 2654208 + 73728 + 27648);  // 64 floats
    float* ms            = stats + 64;                              // 64 floats

    hipMemsetAsync(stats, 0, 64 * sizeof(float), stream);
    k_prep<<<(36864 + 6912 + 255) / 256, 256, 0, stream>>>(cw, ow, wtA, wl_g);
    k_offset<<<dim3(3, WW, BB), 256, 0, stream>>>(f, wl_g, ob, bg, bb, ycum);
    k_main<<<dim3(HH / NT, WW, BB), 256, 0, stream>>>(f, ycum, wtA, cb, out, stats);
    k_stats<<<1, 64, 0, stream>>>(stats, ms);
    k_norm<<<(BB * COUT * WH / 4 + 255) / 256, 256, 0, stream>>>(out, ms, gg, gb);
}

// Round 6
// 275.188 us; speedup vs baseline: 1.4157x; 1.2305x over previous
//
#include <hip/hip_runtime.h>

#define BB 2
#define CIN 64
#define COUT 64
#define KK 9
#define WW 192
#define HH 192
#define WH (WW*HH)
#define CENTER 4
#define NT 32
#define DEFP 584      // padded LDS row length (ck dim), 1168 B rows
#define GROUPS 16
constexpr float EPSV = 1e-5f;
constexpr int NPERG = 4 * WW * HH;

typedef __attribute__((ext_vector_type(8))) short short8v;
typedef __attribute__((ext_vector_type(4))) float float4v;

__device__ __forceinline__ float bf2f(unsigned short u) {
    union { unsigned int i; float f; } x; x.i = ((unsigned int)u) << 16; return x.f;
}
__device__ __forceinline__ unsigned short f2bf(float f) {
    union { float f; unsigned int i; } x; x.f = f;
    unsigned int i = x.i;
    unsigned int r = i + 0x7FFFu + ((i >> 16) & 1u);
    return (unsigned short)(r >> 16);
}

// K0: weight prep. wtA[o][k*64+c] (bf16) for MFMA conv; wl_g[c][tap][12] fp32.
__global__ void k_prep(const float* __restrict__ cw, const float* __restrict__ ow,
                       unsigned short* __restrict__ wtA, float* __restrict__ wl_g)
{
    int i = blockIdx.x * 256 + threadIdx.x;
    if (i < COUT * CIN * KK) {
        int o = i / 576, ck = i % 576;
        int k = ck >> 6, c = ck & 63;
        wtA[i] = f2bf(cw[o * 576 + c * 9 + k]);
    }
    int j2 = i - COUT * CIN * KK;
    if (j2 >= 0 && j2 < CIN * 9 * 12) {
        int c = j2 / 108, rem = j2 % 108, tap = rem / 12, jj = rem % 12;
        wl_g[j2] = (jj < 9) ? ow[jj * 576 + c * 9 + tap] : 0.f;
    }
}

// K-tr: f[0] NCHW -> channels-last bf16 f_t[(y*192+x)][c]
__global__ __launch_bounds__(256) void k_tr(const float* __restrict__ f,
                                            unsigned short* __restrict__ f_t)
{
    __shared__ unsigned short tile[64][72];
    int tid = threadIdx.x;
    int y = blockIdx.y;
    int x0 = blockIdx.x * 64;
    int xl = tid & 63, cq = tid >> 6;  // cq 0..3
#pragma unroll
    for (int ci = 0; ci < 16; ++ci) {
        int c = cq * 16 + ci;
        tile[xl][c] = f2bf(f[c * WH + y * HH + x0 + xl]);
    }
    __syncthreads();
    int cp = tid & 31, xr0 = tid >> 5;  // xr0 0..7
#pragma unroll
    for (int xi = 0; xi < 8; ++xi) {
        int xr = xr0 * 8 + xi;
        unsigned int val = (unsigned int)tile[xr][2 * cp] |
                           ((unsigned int)tile[xr][2 * cp + 1] << 16);
        ((unsigned int*)f_t)[(y * HH + x0 + xr) * 32 + cp] = val;
    }
}

// K1: offset conv + bias + bn + tanh + snake-cumsum. Block 512 = 64 h x 8 c-chunks.
__global__ __launch_bounds__(512) void k_offset(
    const float* __restrict__ f, const float* __restrict__ wl_g,
    const float* __restrict__ ob, const float* __restrict__ bg,
    const float* __restrict__ bb, float* __restrict__ ycum)
{
    __shared__ float4 wl4[1728];      // 27.6 KB
    __shared__ float sacc[64 * 73];   // 18.7 KB
    float* wl = (float*)wl4;

    int tid = threadIdx.x;
    for (int i = tid; i < 1728; i += 512)
        wl4[i] = ((const float4*)wl_g)[i];

    int hl = tid & 63, ch = tid >> 6;  // ch 0..7
    int h = blockIdx.x * 64 + hl;
    int w = blockIdx.y, b = blockIdx.z;
    __syncthreads();

    float acc[9];
#pragma unroll
    for (int j = 0; j < 9; ++j) acc[j] = 0.f;

    const float* fb = f + ((size_t)b * CIN + ch * 8) * WH;
    for (int ci = 0; ci < 8; ++ci) {
        const float* fc = fb + ci * WH;
        const float* wp = wl + (ch * 8 + ci) * 108;
#pragma unroll
        for (int dw = 0; dw < 3; ++dw) {
            int r = w + dw - 1;
            if ((unsigned)r >= WW) continue;
            const float* fr_ = fc + r * HH;
#pragma unroll
            for (int dh = 0; dh < 3; ++dh) {
                int cl = h + dh - 1;
                if ((unsigned)cl >= HH) continue;
                float v = fr_[cl];
                const float* ww = wp + (dw * 3 + dh) * 12;
                float4 wa = *(const float4*)ww;
                float4 wb2 = *(const float4*)(ww + 4);
                float w8 = ww[8];
                acc[0] += v * wa.x;  acc[1] += v * wa.y;
                acc[2] += v * wa.z;  acc[3] += v * wa.w;
                acc[4] += v * wb2.x; acc[5] += v * wb2.y;
                acc[6] += v * wb2.z; acc[7] += v * wb2.w;
                acc[8] += v * w8;
            }
        }
    }
#pragma unroll
    for (int j = 0; j < 9; ++j)
        sacc[hl * 73 + ch * 9 + j] = acc[j];
    __syncthreads();

    if (tid < 64) {
        float s[9];
#pragma unroll
        for (int j = 0; j < 9; ++j) {
            float t0 = 0.f;
#pragma unroll
            for (int c = 0; c < 8; ++c) t0 += sacc[tid * 73 + c * 9 + j];
            s[j] = t0;
        }
        const float inv = 1.0f / sqrtf(1.0f + EPSV);
        float t[9];
#pragma unroll
        for (int j = 0; j < 9; ++j)
            t[j] = tanhf((s[j] + ob[j]) * inv * bg[j] + bb[j]);
        // cumsum quirk: indices 0 and 8 stay raw (loop is range(1, center))
        float cum[9];
        cum[4] = 0.f;
        cum[5] = t[5]; cum[6] = cum[5] + t[6]; cum[7] = cum[6] + t[7];
        cum[3] = t[3]; cum[2] = cum[3] + t[2]; cum[1] = cum[2] + t[1];
        cum[0] = t[0]; cum[8] = t[8];
        int hh = blockIdx.x * 64 + tid;
#pragma unroll
        for (int j = 0; j < 9; ++j)
            ycum[((b * KK + j) * WW + w) * HH + hh] = cum[j];
    }
}

// K2: sample (coalesced via f_t) + MFMA conv + GN partial stats.
__global__ __launch_bounds__(256) void k_main(
    const unsigned short* __restrict__ f_t, const float* __restrict__ ycum,
    const unsigned short* __restrict__ wtA, const float* __restrict__ cb,
    float* __restrict__ zout, float* __restrict__ stats)
{
    __shared__ unsigned short def[NT * DEFP];   // 37.4 KB
    __shared__ short m_y0[KK * NT], m_y1[KK * NT], m_x[KK * NT];
    __shared__ float m_w0[KK * NT], m_w1[KK * NT];

    int tid = threadIdx.x;
    int h0blk = blockIdx.x * NT;
    int w = blockIdx.y;
    int b = blockIdx.z;
    int lane = tid & 63;
    int wid = tid >> 6;
    int lr = lane & 15;
    int lg = lane >> 4;
    int o0 = wid * 16;

    // A-fragments: this wave's 16 output channels, 18 K-steps
    short8v afr[18];
    const unsigned short* wbase = wtA + (o0 + lr) * 576 + lg * 8;
#pragma unroll
    for (int s = 0; s < 18; ++s)
        afr[s] = *(const short8v*)(wbase + s * 32);

    // meta: per (k,h) sampling rows/weights
    for (int p = tid; p < KK * NT; p += 256) {
        int k = p / NT;
        int hl = p % NT;
        int h = h0blk + hl;
        float yf = ycum[((b * KK + k) * WW + w) * HH + h] + (float)w;
        int x = h + k - CENTER;
        float y0f = floorf(yf);
        int iy0 = (int)y0f;
        int y0i = min(max(iy0, 0), WW - 1);
        int y1i = min(max(iy0 + 1, 0), WW - 1);
        float y0w = fminf(fmaxf(y0f, 0.f), (float)WW);
        float y1w = fminf(fmaxf(y0f + 1.f, 0.f), (float)WW);
        float w0 = y1w - yf;
        float w1 = yf - y0w;
        if (x < 0 || x >= HH) { w0 = 0.f; w1 = 0.f; }
        m_y0[p] = (short)y0i;
        m_y1[p] = (short)y1i;
        m_x[p]  = (short)min(max(x, 0), HH - 1);
        m_w0[p] = w0;
        m_w1[p] = w1;
    }
    __syncthreads();

    // stage def[hl][k*64+c]: two coalesced 128B rows per sample, interp in fp32
    for (int it = tid; it < KK * NT * 4; it += 256) {
        int q = it & 3;            // channel quarter (16 ch)
        int p = it >> 2;           // (k,hl) pair
        int y0i = m_y0[p], y1i = m_y1[p], x = m_x[p];
        float w0 = m_w0[p], w1 = m_w1[p];
        const unsigned short* r0 = f_t + ((y0i * HH + x) << 6) + q * 16;
        const unsigned short* r1 = f_t + ((y1i * HH + x) << 6) + q * 16;
        short8v a0 = *(const short8v*)r0;
        short8v a1 = *(const short8v*)(r0 + 8);
        short8v c0 = *(const short8v*)r1;
        short8v c1 = *(const short8v*)(r1 + 8);
        short8v o0v, o1v;
#pragma unroll
        for (int c = 0; c < 8; ++c) {
            float v0 = bf2f((unsigned short)a0[c]) * w0 + bf2f((unsigned short)c0[c]) * w1;
            float v1 = bf2f((unsigned short)a1[c]) * w0 + bf2f((unsigned short)c1[c]) * w1;
            o0v[c] = (short)f2bf(v0);
            o1v[c] = (short)f2bf(v1);
        }
        int hl = p & 31;
        int k = p >> 5;
        unsigned short* d = &def[hl * DEFP + k * 64 + q * 16];
        *(short8v*)d = o0v;
        *(short8v*)(d + 8) = o1v;
    }
    __syncthreads();

    // MFMA: C[16o x 32h] per wave, K=576 in 18 steps
    float4v acc0 = {0.f, 0.f, 0.f, 0.f};
    float4v acc1 = {0.f, 0.f, 0.f, 0.f};
    const unsigned short* drow0 = &def[lr * DEFP + lg * 8];
    const unsigned short* drow1 = &def[(16 + lr) * DEFP + lg * 8];
#pragma unroll
    for (int s = 0; s < 18; ++s) {
        short8v b0 = *(const short8v*)(drow0 + s * 32);
        short8v b1 = *(const short8v*)(drow1 + s * 32);
        acc0 = __builtin_amdgcn_mfma_f32_16x16x32_bf16(afr[s], b0, acc0, 0, 0, 0);
        acc1 = __builtin_amdgcn_mfma_f32_16x16x32_bf16(afr[s], b1, acc1, 0, 0, 0);
    }

    // epilogue: bias, store z, GN partial stats
    float4 cbv = *(const float4*)(cb + o0 + lg * 4);
    float lsum = 0.f, lsq = 0.f;
    size_t base = ((size_t)(b * COUT + o0 + lg * 4) * WW + w) * HH + h0blk + lr;
#pragma unroll
    for (int r = 0; r < 4; ++r) {
        float bias = (r == 0) ? cbv.x : (r == 1) ? cbv.y : (r == 2) ? cbv.z : cbv.w;
        float z0 = acc0[r] + bias;
        float z1 = acc1[r] + bias;
        zout[base + (size_t)r * WH]      = z0;
        zout[base + (size_t)r * WH + 16] = z1;
        lsum += z0 + z1;
        lsq  += z0 * z0 + z1 * z1;
    }
#pragma unroll
    for (int m = 1; m < 16; m <<= 1) {
        lsum += __shfl_xor(lsum, m);
        lsq  += __shfl_xor(lsq, m);
    }
    if (lr == 0) {
        int g = wid * 4 + lg;
        atomicAdd(&stats[b * GROUPS + g], lsum);
        atomicAdd(&stats[BB * GROUPS + b * GROUPS + g], lsq);
    }
}

// K3: finalize GN stats
__global__ void k_stats(const float* __restrict__ stats, float* __restrict__ ms)
{
    int i = threadIdx.x;
    if (i >= BB * GROUPS) return;
    float s = stats[i];
    float q = stats[BB * GROUPS + i];
    float mean = s / (float)NPERG;
    float var = q / (float)NPERG - mean * mean;
    ms[i] = mean;
    ms[BB * GROUPS + i] = 1.0f / sqrtf(var + EPSV);
}

// K4: normalize + affine + relu, in place on d_out
__global__ __launch_bounds__(256) void k_norm(
    float* __restrict__ z, const float* __restrict__ ms,
    const float* __restrict__ gg, const float* __restrict__ gb)
{
    int i = blockIdx.x * 256 + threadIdx.x;
    const int total4 = BB * COUT * WW * HH / 4;
    if (i >= total4) return;
    float4 v = ((float4*)z)[i];
    int idx = i * 4;
    int o = (idx / WH) % COUT;
    int b = idx / (COUT * WH);
    int g = o >> 2;
    float mean = ms[b * GROUPS + g];
    float istd = ms[BB * GROUPS + b * GROUPS + g];
    float ga = gg[o], be = gb[o];
    v.x = fmaxf((v.x - mean) * istd * ga + be, 0.f);
    v.y = fmaxf((v.y - mean) * istd * ga + be, 0.f);
    v.z = fmaxf((v.z - mean) * istd * ga + be, 0.f);
    v.w = fmaxf((v.w - mean) * istd * ga + be, 0.f);
    ((float4*)z)[i] = v;
}

extern "C" void kernel_launch(void* const* d_in, const int* in_sizes, int n_in,
                              void* d_out, int out_size, void* d_ws, size_t ws_size,
                              hipStream_t stream)
{
    const float* f  = (const float*)d_in[0];
    const float* ow = (const float*)d_in[1];
    const float* ob = (const float*)d_in[2];
    const float* bg = (const float*)d_in[3];
    const float* bb = (const float*)d_in[4];
    const float* cw = (const float*)d_in[5];
    const float* cb = (const float*)d_in[6];
    const float* gg = (const float*)d_in[7];
    const float* gb = (const float*)d_in[8];
    float* out = (float*)d_out;

    char* ws = (char*)d_ws;
    unsigned short* f_t  = (unsigned short*)ws;                     // 4,718,592 B
    float* ycum          = (float*)(ws + 4718592);                  // 2,654,208 B
    unsigned short* wtA  = (unsigned short*)(ws + 4718592 + 2654208);       // 73,728 B
    float* wl_g          = (float*)(ws + 4718592 + 2654208 + 73728);        // 27,648 B
    float* stats         = (float*)(ws + 4718592 + 2654208 + 73728 + 27648);
    float* ms            = stats + 64;

    hipMemsetAsync(stats, 0, 64 * sizeof(float), stream);
    k_prep<<<(36864 + 6912 + 255) / 256, 256, 0, stream>>>(cw, ow, wtA, wl_g);
    k_tr<<<dim3(3, WW), 256, 0, stream>>>(f, f_t);
    k_offset<<<dim3(3, WW, BB), 512, 0, stream>>>(f, wl_g, ob, bg, bb, ycum);
    k_main<<<dim3(HH / NT, WW, BB), 256, 0, stream>>>(f_t, ycum, wtA, cb, out, stats);
    k_stats<<<1, 64, 0, stream>>>(stats, ms);
    k_norm<<<(BB * COUT * WH / 4 + 255) / 256, 256, 0, stream>>>(out, ms, gg, gb);
}

// Round 9
// 198.732 us; speedup vs baseline: 1.9604x; 1.3847x over previous
//
#include <hip/hip_runtime.h>

#define BB 2
#define CIN 64
#define COUT 64
#define KK 9
#define WW 192
#define HH 192
#define WH (WW*HH)
#define CENTER 4
#define NT 32
#define DEFP 584      // padded LDS row length (ck dim), 1168 B rows
#define GROUPS 16
constexpr float EPSV = 1e-5f;
constexpr int NPERG = 4 * WH;

typedef __attribute__((ext_vector_type(8))) short short8v;
typedef __attribute__((ext_vector_type(4))) float float4v;

__device__ __forceinline__ float bf2f(unsigned short u) {
    union { unsigned int i; float f; } x; x.i = ((unsigned int)u) << 16; return x.f;
}
__device__ __forceinline__ unsigned short f2bf(float f) {
    union { float f; unsigned int i; } x; x.f = f;
    unsigned int i = x.i;
    unsigned int r = i + 0x7FFFu + ((i >> 16) & 1u);
    return (unsigned short)(r >> 16);
}

// K0: weight prep. wtA[o][k*64+c] (bf16) for MFMA conv; wl_g[c][tap][12] fp32.
__global__ void k_prep(const float* __restrict__ cw, const float* __restrict__ ow,
                       unsigned short* __restrict__ wtA, float* __restrict__ wl_g)
{
    int i = blockIdx.x * 256 + threadIdx.x;
    if (i < COUT * CIN * KK) {
        int o = i / 576, ck = i % 576;
        int k = ck >> 6, c = ck & 63;
        wtA[i] = f2bf(cw[o * 576 + c * 9 + k]);
    }
    int j2 = i - COUT * CIN * KK;
    if (j2 >= 0 && j2 < CIN * 9 * 12) {
        int c = j2 / 108, rem = j2 % 108, tap = rem / 12, jj = rem % 12;
        wl_g[j2] = (jj < 9) ? ow[jj * 576 + c * 9 + tap] : 0.f;
    }
}

// K1: f[0] NCHW -> channels-last bf16 f_t[(y*192+x)][c]
__global__ __launch_bounds__(256) void k_tr(const float* __restrict__ f,
                                            unsigned short* __restrict__ f_t)
{
    __shared__ unsigned short tile[64][72];
    int tid = threadIdx.x;
    int y = blockIdx.y;
    int x0 = blockIdx.x * 64;
    int xl = tid & 63, cq = tid >> 6;  // cq 0..3
#pragma unroll
    for (int ci = 0; ci < 16; ++ci) {
        int c = cq * 16 + ci;
        tile[xl][c] = f2bf(f[c * WH + y * HH + x0 + xl]);
    }
    __syncthreads();
    int cp = tid & 31, xr0 = tid >> 5;  // xr0 0..7
#pragma unroll
    for (int xi = 0; xi < 8; ++xi) {
        int xr = xr0 * 8 + xi;
        unsigned int val = (unsigned int)tile[xr][2 * cp] |
                           ((unsigned int)tile[xr][2 * cp + 1] << 16);
        ((unsigned int*)f_t)[(y * HH + x0 + xr) * 32 + cp] = val;
    }
}

// K2: offset conv + bias + bn + tanh + snake-cumsum. Block 512 = 64 h x 8 c-chunks.
__global__ __launch_bounds__(512) void k_offset(
    const float* __restrict__ f, const float* __restrict__ wl_g,
    const float* __restrict__ ob, const float* __restrict__ bg,
    const float* __restrict__ bb, float* __restrict__ ycum)
{
    __shared__ float4 wl4[1728];      // 27.6 KB
    __shared__ float sacc[64 * 73];   // 18.7 KB
    float* wl = (float*)wl4;

    int tid = threadIdx.x;
    for (int i = tid; i < 1728; i += 512)
        wl4[i] = ((const float4*)wl_g)[i];

    int hl = tid & 63, ch = tid >> 6;  // ch 0..7
    int h = blockIdx.x * 64 + hl;
    int w = blockIdx.y, b = blockIdx.z;
    __syncthreads();

    float acc[9];
#pragma unroll
    for (int j = 0; j < 9; ++j) acc[j] = 0.f;

    const float* fb = f + ((size_t)b * CIN + ch * 8) * WH;
    for (int ci = 0; ci < 8; ++ci) {
        const float* fc = fb + ci * WH;
        const float* wp = wl + (ch * 8 + ci) * 108;
#pragma unroll
        for (int dw = 0; dw < 3; ++dw) {
            int r = w + dw - 1;
            if ((unsigned)r >= WW) continue;
            const float* fr_ = fc + r * HH;
#pragma unroll
            for (int dh = 0; dh < 3; ++dh) {
                int cl = h + dh - 1;
                if ((unsigned)cl >= HH) continue;
                float v = fr_[cl];
                const float* ww = wp + (dw * 3 + dh) * 12;
                float4 wa = *(const float4*)ww;
                float4 wb2 = *(const float4*)(ww + 4);
                float w8 = ww[8];
                acc[0] += v * wa.x;  acc[1] += v * wa.y;
                acc[2] += v * wa.z;  acc[3] += v * wa.w;
                acc[4] += v * wb2.x; acc[5] += v * wb2.y;
                acc[6] += v * wb2.z; acc[7] += v * wb2.w;
                acc[8] += v * w8;
            }
        }
    }
#pragma unroll
    for (int j = 0; j < 9; ++j)
        sacc[hl * 73 + ch * 9 + j] = acc[j];
    __syncthreads();

    if (tid < 64) {
        float s[9];
#pragma unroll
        for (int j = 0; j < 9; ++j) {
            float t0 = 0.f;
#pragma unroll
            for (int c = 0; c < 8; ++c) t0 += sacc[tid * 73 + c * 9 + j];
            s[j] = t0;
        }
        const float inv = 1.0f / sqrtf(1.0f + EPSV);
        float t[9];
#pragma unroll
        for (int j = 0; j < 9; ++j)
            t[j] = tanhf((s[j] + ob[j]) * inv * bg[j] + bb[j]);
        // cumsum quirk: indices 0 and 8 stay raw (loop is range(1, center))
        float cum[9];
        cum[4] = 0.f;
        cum[5] = t[5]; cum[6] = cum[5] + t[6]; cum[7] = cum[6] + t[7];
        cum[3] = t[3]; cum[2] = cum[3] + t[2]; cum[1] = cum[2] + t[1];
        cum[0] = t[0]; cum[8] = t[8];
        int hh = blockIdx.x * 64 + tid;
#pragma unroll
        for (int j = 0; j < 9; ++j)
            ycum[((b * KK + j) * WW + w) * HH + hh] = cum[j];
    }
}

// K3: sample (coalesced via f_t) + MFMA conv. NO atomics.
__global__ __launch_bounds__(256) void k_main(
    const unsigned short* __restrict__ f_t, const float* __restrict__ ycum,
    const unsigned short* __restrict__ wtA, const float* __restrict__ cb,
    float* __restrict__ zout)
{
    __shared__ unsigned short def[NT * DEFP];   // 37.4 KB
    __shared__ short m_y0[KK * NT], m_y1[KK * NT], m_x[KK * NT];
    __shared__ float m_w0[KK * NT], m_w1[KK * NT];

    int tid = threadIdx.x;
    int h0blk = blockIdx.x * NT;
    int w = blockIdx.y;
    int b = blockIdx.z;
    int lane = tid & 63;
    int wid = tid >> 6;
    int lr = lane & 15;
    int lg = lane >> 4;
    int o0 = wid * 16;

    // A-fragments: this wave's 16 output channels, 18 K-steps
    short8v afr[18];
    const unsigned short* wbase = wtA + (o0 + lr) * 576 + lg * 8;
#pragma unroll
    for (int s = 0; s < 18; ++s)
        afr[s] = *(const short8v*)(wbase + s * 32);

    // meta: per (k,h) sampling rows/weights
    for (int p = tid; p < KK * NT; p += 256) {
        int k = p / NT;
        int hl = p % NT;
        int h = h0blk + hl;
        float yf = ycum[((b * KK + k) * WW + w) * HH + h] + (float)w;
        int x = h + k - CENTER;
        float y0f = floorf(yf);
        int iy0 = (int)y0f;
        int y0i = min(max(iy0, 0), WW - 1);
        int y1i = min(max(iy0 + 1, 0), WW - 1);
        float y0w = fminf(fmaxf(y0f, 0.f), (float)WW);
        float y1w = fminf(fmaxf(y0f + 1.f, 0.f), (float)WW);
        float w0 = y1w - yf;
        float w1 = yf - y0w;
        if (x < 0 || x >= HH) { w0 = 0.f; w1 = 0.f; }
        m_y0[p] = (short)y0i;
        m_y1[p] = (short)y1i;
        m_x[p]  = (short)min(max(x, 0), HH - 1);
        m_w0[p] = w0;
        m_w1[p] = w1;
    }
    __syncthreads();

    // stage def[hl][k*64+c]: two coalesced 128B rows per sample, interp in fp32
    for (int it = tid; it < KK * NT * 4; it += 256) {
        int q = it & 3;            // channel quarter (16 ch)
        int p = it >> 2;           // (k,hl) pair
        int y0i = m_y0[p], y1i = m_y1[p], x = m_x[p];
        float w0 = m_w0[p], w1 = m_w1[p];
        const unsigned short* r0 = f_t + ((y0i * HH + x) << 6) + q * 16;
        const unsigned short* r1 = f_t + ((y1i * HH + x) << 6) + q * 16;
        short8v a0 = *(const short8v*)r0;
        short8v a1 = *(const short8v*)(r0 + 8);
        short8v c0 = *(const short8v*)r1;
        short8v c1 = *(const short8v*)(r1 + 8);
        short8v o0v, o1v;
#pragma unroll
        for (int c = 0; c < 8; ++c) {
            float v0 = bf2f((unsigned short)a0[c]) * w0 + bf2f((unsigned short)c0[c]) * w1;
            float v1 = bf2f((unsigned short)a1[c]) * w0 + bf2f((unsigned short)c1[c]) * w1;
            o0v[c] = (short)f2bf(v0);
            o1v[c] = (short)f2bf(v1);
        }
        int hl = p & 31;
        int k = p >> 5;
        unsigned short* d = &def[hl * DEFP + k * 64 + q * 16];
        *(short8v*)d = o0v;
        *(short8v*)(d + 8) = o1v;
    }
    __syncthreads();

    // MFMA: C[16o x 32h] per wave, K=576 in 18 steps
    float4v acc0 = {0.f, 0.f, 0.f, 0.f};
    float4v acc1 = {0.f, 0.f, 0.f, 0.f};
    const unsigned short* drow0 = &def[lr * DEFP + lg * 8];
    const unsigned short* drow1 = &def[(16 + lr) * DEFP + lg * 8];
#pragma unroll
    for (int s = 0; s < 18; ++s) {
        short8v b0 = *(const short8v*)(drow0 + s * 32);
        short8v b1 = *(const short8v*)(drow1 + s * 32);
        acc0 = __builtin_amdgcn_mfma_f32_16x16x32_bf16(afr[s], b0, acc0, 0, 0, 0);
        acc1 = __builtin_amdgcn_mfma_f32_16x16x32_bf16(afr[s], b1, acc1, 0, 0, 0);
    }

    // epilogue: bias + store z
    float4 cbv = *(const float4*)(cb + o0 + lg * 4);
    size_t base = ((size_t)(b * COUT + o0 + lg * 4) * WW + w) * HH + h0blk + lr;
#pragma unroll
    for (int r = 0; r < 4; ++r) {
        float bias = (r == 0) ? cbv.x : (r == 1) ? cbv.y : (r == 2) ? cbv.z : cbv.w;
        zout[base + (size_t)r * WH]      = acc0[r] + bias;
        zout[base + (size_t)r * WH + 16] = acc1[r] + bias;
    }
}

// K4: GN stats, one block per (b, group), no atomics
__global__ __launch_bounds__(1024) void k_gstats(const float* __restrict__ z,
                                                 float* __restrict__ ms)
{
    __shared__ float sL[16], qL[16];
    int b = blockIdx.x >> 4, g = blockIdx.x & 15;
    const float4* p = (const float4*)(z + ((size_t)b * COUT + g * 4) * WH);
    float s = 0.f, q = 0.f;
    for (int i = threadIdx.x; i < WH; i += 1024) {  // 4ch * WH floats = WH float4s
        float4 v = p[i];
        s += v.x + v.y + v.z + v.w;
        q += v.x * v.x + v.y * v.y + v.z * v.z + v.w * v.w;
    }
#pragma unroll
    for (int m = 1; m < 64; m <<= 1) {
        s += __shfl_xor(s, m);
        q += __shfl_xor(q, m);
    }
    int wv = threadIdx.x >> 6;
    if ((threadIdx.x & 63) == 0) { sL[wv] = s; qL[wv] = q; }
    __syncthreads();
    if (threadIdx.x == 0) {
        float ts = 0.f, tq = 0.f;
#pragma unroll
        for (int i = 0; i < 16; ++i) { ts += sL[i]; tq += qL[i]; }
        float mean = ts / (float)NPERG;
        float var = tq / (float)NPERG - mean * mean;
        ms[b * GROUPS + g] = mean;
        ms[BB * GROUPS + b * GROUPS + g] = 1.0f / sqrtf(var + EPSV);
    }
}

// K5: normalize + affine + relu, in place on d_out
__global__ __launch_bounds__(256) void k_norm(
    float* __restrict__ z, const float* __restrict__ ms,
    const float* __restrict__ gg, const float* __restrict__ gb)
{
    int i = blockIdx.x * 256 + threadIdx.x;
    const int total4 = BB * COUT * WH / 4;
    if (i >= total4) return;
    float4 v = ((float4*)z)[i];
    int idx = i * 4;
    int o = (idx / WH) % COUT;
    int b = idx / (COUT * WH);
    int g = o >> 2;
    float mean = ms[b * GROUPS + g];
    float istd = ms[BB * GROUPS + b * GROUPS + g];
    float ga = gg[o], be = gb[o];
    v.x = fmaxf((v.x - mean) * istd * ga + be, 0.f);
    v.y = fmaxf((v.y - mean) * istd * ga + be, 0.f);
    v.z = fmaxf((v.z - mean) * istd * ga + be, 0.f);
    v.w = fmaxf((v.w - mean) * istd * ga + be, 0.f);
    ((float4*)z)[i] = v;
}

extern "C" void kernel_launch(void* const* d_in, const int* in_sizes, int n_in,
                              void* d_out, int out_size, void* d_ws, size_t ws_size,
                              hipStream_t stream)
{
    const float* f  = (const float*)d_in[0];
    const float* ow = (const float*)d_in[1];
    const float* ob = (const float*)d_in[2];
    const float* bg = (const float*)d_in[3];
    const float* bb = (const float*)d_in[4];
    const float* cw = (const float*)d_in[5];
    const float* cb = (const float*)d_in[6];
    const float* gg = (const float*)d_in[7];
    const float* gb = (const float*)d_in[8];
    float* out = (float*)d_out;

    char* ws = (char*)d_ws;
    unsigned short* f_t  = (unsigned short*)ws;                       // 4,718,592 B
    float* ycum          = (float*)(ws + 4718592);                    // 2,654,208 B
    unsigned short* wtA  = (unsigned short*)(ws + 4718592 + 2654208); // 73,728 B
    float* wl_g          = (float*)(ws + 4718592 + 2654208 + 73728);  // 27,648 B
    float* ms            = (float*)(ws + 4718592 + 2654208 + 73728 + 27648); // 256 B

    k_prep<<<(36864 + 6912 + 255) / 256, 256, 0, stream>>>(cw, ow, wtA, wl_g);
    k_tr<<<dim3(3, WW), 256, 0, stream>>>(f, f_t);
    k_offset<<<dim3(3, WW, BB), 512, 0, stream>>>(f, wl_g, ob, bg, bb, ycum);
    k_main<<<dim3(HH / NT, WW, BB), 256, 0, stream>>>(f_t, ycum, wtA, cb, out);
    k_gstats<<<BB * GROUPS, 1024, 0, stream>>>(out, ms);
    k_norm<<<(BB * COUT * WH / 4 + 255) / 256, 256, 0, stream>>>(out, ms, gg, gb);
}

// Round 11
// 187.899 us; speedup vs baseline: 2.0734x; 1.0577x over previous
//
#include <hip/hip_runtime.h>

#define BB 2
#define CIN 64
#define COUT 64
#define KK 9
#define WW 192
#define HH 192
#define WH (WW*HH)
#define CENTER 4
#define NT 32
#define DEFP 584      // padded LDS row length (ck dim), 1168 B rows
#define GROUPS 16
constexpr float EPSV = 1e-5f;
constexpr int NPERG = 4 * WH;

typedef __attribute__((ext_vector_type(8))) short short8v;
typedef __attribute__((ext_vector_type(4))) float float4v;

__device__ __forceinline__ float bf2f(unsigned short u) {
    union { unsigned int i; float f; } x; x.i = ((unsigned int)u) << 16; return x.f;
}
__device__ __forceinline__ unsigned short f2bf(float f) {
    union { float f; unsigned int i; } x; x.f = f;
    unsigned int i = x.i;
    unsigned int r = i + 0x7FFFu + ((i >> 16) & 1u);
    return (unsigned short)(r >> 16);
}

// K0: weight prep. wtA[o][k*64+c] (bf16) for MFMA conv; wl_g[c][tap][12] fp32.
__global__ void k_prep(const float* __restrict__ cw, const float* __restrict__ ow,
                       unsigned short* __restrict__ wtA, float* __restrict__ wl_g)
{
    int i = blockIdx.x * 256 + threadIdx.x;
    if (i < COUT * CIN * KK) {
        int o = i / 576, ck = i % 576;
        int k = ck >> 6, c = ck & 63;
        wtA[i] = f2bf(cw[o * 576 + c * 9 + k]);
    }
    int j2 = i - COUT * CIN * KK;
    if (j2 >= 0 && j2 < CIN * 9 * 12) {
        int c = j2 / 108, rem = j2 % 108, tap = rem / 12, jj = rem % 12;
        wl_g[j2] = (jj < 9) ? ow[jj * 576 + c * 9 + tap] : 0.f;
    }
}

// K1: f[0] NCHW -> channels-last bf16 f_t[(y*192+x)][c]
__global__ __launch_bounds__(256) void k_tr(const float* __restrict__ f,
                                            unsigned short* __restrict__ f_t)
{
    __shared__ unsigned short tile[64][72];
    int tid = threadIdx.x;
    int y = blockIdx.y;
    int x0 = blockIdx.x * 64;
    int xl = tid & 63, cq = tid >> 6;  // cq 0..3
#pragma unroll
    for (int ci = 0; ci < 16; ++ci) {
        int c = cq * 16 + ci;
        tile[xl][c] = f2bf(f[c * WH + y * HH + x0 + xl]);
    }
    __syncthreads();
    int cp = tid & 31, xr0 = tid >> 5;  // xr0 0..7
#pragma unroll
    for (int xi = 0; xi < 8; ++xi) {
        int xr = xr0 * 8 + xi;
        unsigned int val = (unsigned int)tile[xr][2 * cp] |
                           ((unsigned int)tile[xr][2 * cp + 1] << 16);
        ((unsigned int*)f_t)[(y * HH + x0 + xr) * 32 + cp] = val;
    }
}

// K2: fused: fp32 offset conv + tanh/cumsum + deform-sample + MFMA conv.
// Block 256 (4 waves); grid (H/NT, W, B). Sampling always from f_t[0] (ref quirk).
__global__ __launch_bounds__(256) void k_fused(
    const float* __restrict__ f, const unsigned short* __restrict__ f_t,
    const float* __restrict__ wl_g, const unsigned short* __restrict__ wtA,
    const float* __restrict__ ob, const float* __restrict__ bg,
    const float* __restrict__ bb, const float* __restrict__ cb,
    float* __restrict__ zout)
{
    __shared__ float4 wl4[1728];                // 27.6 KB (offset weights, fp32)
    __shared__ unsigned short def[NT * DEFP];   // 37.4 KB (phase A: partials; phase B: tiles)
    __shared__ short m_y0[KK * NT], m_y1[KK * NT], m_x[KK * NT];
    __shared__ float m_w0[KK * NT], m_w1[KK * NT];
    float* wl = (float*)wl4;
    float* part = (float*)def;                  // [c8][p][9] fp32 partials (9.2 KB)

    int tid = threadIdx.x;
    int h0 = blockIdx.x * NT;
    int w = blockIdx.y;
    int b = blockIdx.z;
    int lane = tid & 63;
    int wid = tid >> 6;
    int lr = lane & 15;
    int lg = lane >> 4;
    int o0 = wid * 16;

    for (int i = tid; i < 1728; i += 256)
        wl4[i] = ((const float4*)wl_g)[i];

    // ---- phase A: fp32 offset conv, thread = (pixel p, channel-octet c8) ----
    int p = tid & 31, c8 = tid >> 5;
    float acc[9];
#pragma unroll
    for (int j = 0; j < 9; ++j) acc[j] = 0.f;
    const float* fb = f + ((size_t)b * CIN + c8 * 8) * WH;
    __syncthreads();   // wl ready

#pragma unroll
    for (int tap = 0; tap < 9; ++tap) {
        int r = w + tap / 3 - 1;
        int cl = h0 + p + tap % 3 - 1;
        if ((unsigned)r >= WW || (unsigned)cl >= HH) continue;
        const float* src = fb + r * HH + cl;
#pragma unroll
        for (int cc = 0; cc < 8; ++cc) {
            float v = src[cc * WH];
            const float* ww = wl + (c8 * 8 + cc) * 108 + tap * 12;
            float4 wa = *(const float4*)ww;
            float4 wb2 = *(const float4*)(ww + 4);
            float w8 = ww[8];
            acc[0] += v * wa.x;  acc[1] += v * wa.y;
            acc[2] += v * wa.z;  acc[3] += v * wa.w;
            acc[4] += v * wb2.x; acc[5] += v * wb2.y;
            acc[6] += v * wb2.z; acc[7] += v * wb2.w;
            acc[8] += v * w8;
        }
    }
#pragma unroll
    for (int j = 0; j < 9; ++j)
        part[(c8 * 32 + p) * 9 + j] = acc[j];

    // A-fragments for the main conv (overlap load latency with meta phase)
    short8v afr[18];
    const unsigned short* wbase = wtA + (o0 + lr) * 576 + lg * 8;
#pragma unroll
    for (int s = 0; s < 18; ++s)
        afr[s] = *(const short8v*)(wbase + s * 32);
    __syncthreads();

    // ---- reduce partials + tanh + snake-cumsum + sampling meta ----
    if (tid < NT) {
        float s[9];
#pragma unroll
        for (int j = 0; j < 9; ++j) {
            float t0 = 0.f;
#pragma unroll
            for (int g = 0; g < 8; ++g) t0 += part[(g * 32 + tid) * 9 + j];
            s[j] = t0;
        }
        const float inv = 1.0f / sqrtf(1.0f + EPSV);
        float t[9];
#pragma unroll
        for (int j = 0; j < 9; ++j)
            t[j] = tanhf((s[j] + ob[j]) * inv * bg[j] + bb[j]);
        // cumsum quirk: indices 0 and 8 stay raw (loop is range(1, center))
        float cum[9];
        cum[4] = 0.f;
        cum[5] = t[5]; cum[6] = cum[5] + t[6]; cum[7] = cum[6] + t[7];
        cum[3] = t[3]; cum[2] = cum[3] + t[2]; cum[1] = cum[2] + t[1];
        cum[0] = t[0]; cum[8] = t[8];
        int h = h0 + tid;
#pragma unroll
        for (int k = 0; k < 9; ++k) {
            float yf = cum[k] + (float)w;
            int x = h + k - CENTER;
            float y0f = floorf(yf);
            int iy0 = (int)y0f;
            int y0i = min(max(iy0, 0), WW - 1);
            int y1i = min(max(iy0 + 1, 0), WW - 1);
            float y0w = fminf(fmaxf(y0f, 0.f), (float)WW);
            float y1w = fminf(fmaxf(y0f + 1.f, 0.f), (float)WW);
            float w0 = y1w - yf;
            float w1 = yf - y0w;
            if (x < 0 || x >= HH) { w0 = 0.f; w1 = 0.f; }
            int pp = k * NT + tid;
            m_y0[pp] = (short)y0i;
            m_y1[pp] = (short)y1i;
            m_x[pp]  = (short)min(max(x, 0), HH - 1);
            m_w0[pp] = w0;
            m_w1[pp] = w1;
        }
    }
    __syncthreads();

    // ---- phase B staging: def[hl][k*64+c], bilinear in y from f_t[0] ----
    for (int it = tid; it < KK * NT * 4; it += 256) {
        int q = it & 3;            // channel quarter (16 ch)
        int pp = it >> 2;          // (k,hl) pair
        int y0i = m_y0[pp], y1i = m_y1[pp], x = m_x[pp];
        float w0 = m_w0[pp], w1 = m_w1[pp];
        const unsigned short* r0 = f_t + ((y0i * HH + x) << 6) + q * 16;
        const unsigned short* r1 = f_t + ((y1i * HH + x) << 6) + q * 16;
        short8v a0 = *(const short8v*)r0;
        short8v a1 = *(const short8v*)(r0 + 8);
        short8v c0 = *(const short8v*)r1;
        short8v c1 = *(const short8v*)(r1 + 8);
        short8v o0v, o1v;
#pragma unroll
        for (int c = 0; c < 8; ++c) {
            float v0 = bf2f((unsigned short)a0[c]) * w0 + bf2f((unsigned short)c0[c]) * w1;
            float v1 = bf2f((unsigned short)a1[c]) * w0 + bf2f((unsigned short)c1[c]) * w1;
            o0v[c] = (short)f2bf(v0);
            o1v[c] = (short)f2bf(v1);
        }
        int hl = pp & 31;
        int k = pp >> 5;
        unsigned short* d = &def[hl * DEFP + k * 64 + q * 16];
        *(short8v*)d = o0v;
        *(short8v*)(d + 8) = o1v;
    }
    __syncthreads();

    // ---- phase B MFMA: C[16o x 32h] per wave, K=576 in 18 steps ----
    float4v acc0 = {0.f, 0.f, 0.f, 0.f};
    float4v acc1 = {0.f, 0.f, 0.f, 0.f};
    const unsigned short* drow0 = &def[lr * DEFP + lg * 8];
    const unsigned short* drow1 = &def[(16 + lr) * DEFP + lg * 8];
#pragma unroll
    for (int s = 0; s < 18; ++s) {
        short8v b0 = *(const short8v*)(drow0 + s * 32);
        short8v b1 = *(const short8v*)(drow1 + s * 32);
        acc0 = __builtin_amdgcn_mfma_f32_16x16x32_bf16(afr[s], b0, acc0, 0, 0, 0);
        acc1 = __builtin_amdgcn_mfma_f32_16x16x32_bf16(afr[s], b1, acc1, 0, 0, 0);
    }

    // epilogue: bias + store z
    float4 cbv = *(const float4*)(cb + o0 + lg * 4);
    size_t base = ((size_t)(b * COUT + o0 + lg * 4) * WW + w) * HH + h0 + lr;
#pragma unroll
    for (int r = 0; r < 4; ++r) {
        float bias = (r == 0) ? cbv.x : (r == 1) ? cbv.y : (r == 2) ? cbv.z : cbv.w;
        zout[base + (size_t)r * WH]      = acc0[r] + bias;
        zout[base + (size_t)r * WH + 16] = acc1[r] + bias;
    }
}

// K3: GN stats, one block per (b, group), no atomics
__global__ __launch_bounds__(1024) void k_gstats(const float* __restrict__ z,
                                                 float* __restrict__ ms)
{
    __shared__ float sL[16], qL[16];
    int b = blockIdx.x >> 4, g = blockIdx.x & 15;
    const float4* p = (const float4*)(z + ((size_t)b * COUT + g * 4) * WH);
    float s = 0.f, q = 0.f;
    for (int i = threadIdx.x; i < WH; i += 1024) {
        float4 v = p[i];
        s += v.x + v.y + v.z + v.w;
        q += v.x * v.x + v.y * v.y + v.z * v.z + v.w * v.w;
    }
#pragma unroll
    for (int m = 1; m < 64; m <<= 1) {
        s += __shfl_xor(s, m);
        q += __shfl_xor(q, m);
    }
    int wv = threadIdx.x >> 6;
    if ((threadIdx.x & 63) == 0) { sL[wv] = s; qL[wv] = q; }
    __syncthreads();
    if (threadIdx.x == 0) {
        float ts = 0.f, tq = 0.f;
#pragma unroll
        for (int i = 0; i < 16; ++i) { ts += sL[i]; tq += qL[i]; }
        float mean = ts / (float)NPERG;
        float var = tq / (float)NPERG - mean * mean;
        ms[b * GROUPS + g] = mean;
        ms[BB * GROUPS + b * GROUPS + g] = 1.0f / sqrtf(var + EPSV);
    }
}

// K4: normalize + affine + relu, in place on d_out
__global__ __launch_bounds__(256) void k_norm(
    float* __restrict__ z, const float* __restrict__ ms,
    const float* __restrict__ gg, const float* __restrict__ gb)
{
    int i = blockIdx.x * 256 + threadIdx.x;
    const int total4 = BB * COUT * WH / 4;
    if (i >= total4) return;
    float4 v = ((float4*)z)[i];
    int idx = i * 4;
    int o = (idx / WH) % COUT;
    int b = idx / (COUT * WH);
    int g = o >> 2;
    float mean = ms[b * GROUPS + g];
    float istd = ms[BB * GROUPS + b * GROUPS + g];
    float ga = gg[o], be = gb[o];
    v.x = fmaxf((v.x - mean) * istd * ga + be, 0.f);
    v.y = fmaxf((v.y - mean) * istd * ga + be, 0.f);
    v.z = fmaxf((v.z - mean) * istd * ga + be, 0.f);
    v.w = fmaxf((v.w - mean) * istd * ga + be, 0.f);
    ((float4*)z)[i] = v;
}

extern "C" void kernel_launch(void* const* d_in, const int* in_sizes, int n_in,
                              void* d_out, int out_size, void* d_ws, size_t ws_size,
                              hipStream_t stream)
{
    const float* f  = (const float*)d_in[0];
    const float* ow = (const float*)d_in[1];
    const float* ob = (const float*)d_in[2];
    const float* bg = (const float*)d_in[3];
    const float* bb = (const float*)d_in[4];
    const float* cw = (const float*)d_in[5];
    const float* cb = (const float*)d_in[6];
    const float* gg = (const float*)d_in[7];
    const float* gb = (const float*)d_in[8];
    float* out = (float*)d_out;

    char* ws = (char*)d_ws;
    unsigned short* f_t = (unsigned short*)ws;                      // 4,718,592 B
    unsigned short* wtA = (unsigned short*)(ws + 4718592);          // 73,728 B
    float* wl_g         = (float*)(ws + 4718592 + 73728);           // 27,648 B
    float* ms           = (float*)(ws + 4718592 + 73728 + 27648);   // 256 B

    k_prep<<<(36864 + 6912 + 255) / 256, 256, 0, stream>>>(cw, ow, wtA, wl_g);
    k_tr<<<dim3(3, WW), 256, 0, stream>>>(f, f_t);
    k_fused<<<dim3(HH / NT, WW, BB), 256, 0, stream>>>(f, f_t, wl_g, wtA, ob, bg, bb, cb, out);
    k_gstats<<<BB * GROUPS, 1024, 0, stream>>>(out, ms);
    k_norm<<<(BB * COUT * WH / 4 + 255) / 256, 256, 0, stream>>>(out, ms, gg, gb);
}

// Round 12
// 165.339 us; speedup vs baseline: 2.3563x; 1.1364x over previous
//
#include <hip/hip_runtime.h>

#define BB 2
#define CIN 64
#define COUT 64
#define KK 9
#define WW 192
#define HH 192
#define WH (WW*HH)
#define CENTER 4
#define NT 32
#define DEFP 584      // padded LDS row length (ck dim), 1168 B rows
#define GROUPS 16
#define NBLK 2304     // 8 XCD chunks x 288
constexpr float EPSV = 1e-5f;
constexpr int NPERG = 4 * WH;

typedef __attribute__((ext_vector_type(8))) short short8v;
typedef __attribute__((ext_vector_type(4))) float float4v;

__device__ __forceinline__ float bf2f(unsigned short u) {
    union { unsigned int i; float f; } x; x.i = ((unsigned int)u) << 16; return x.f;
}
__device__ __forceinline__ unsigned short f2bf(float f) {
    union { float f; unsigned int i; } x; x.f = f;
    unsigned int i = x.i;
    unsigned int r = i + 0x7FFFu + ((i >> 16) & 1u);
    return (unsigned short)(r >> 16);
}

// K0: weight prep. wtA[o][k*64+c] (bf16) for MFMA conv; wl_g[c][tap][12] fp32.
__global__ void k_prep(const float* __restrict__ cw, const float* __restrict__ ow,
                       unsigned short* __restrict__ wtA, float* __restrict__ wl_g)
{
    int i = blockIdx.x * 256 + threadIdx.x;
    if (i < COUT * CIN * KK) {
        int o = i / 576, ck = i % 576;
        int k = ck >> 6, c = ck & 63;
        wtA[i] = f2bf(cw[o * 576 + c * 9 + k]);
    }
    int j2 = i - COUT * CIN * KK;
    if (j2 >= 0 && j2 < CIN * 9 * 12) {
        int c = j2 / 108, rem = j2 % 108, tap = rem / 12, jj = rem % 12;
        wl_g[j2] = (jj < 9) ? ow[jj * 576 + c * 9 + tap] : 0.f;
    }
}

// K1: f[0] NCHW -> channels-last bf16 f_t[(y*192+x)][c]
__global__ __launch_bounds__(256) void k_tr(const float* __restrict__ f,
                                            unsigned short* __restrict__ f_t)
{
    __shared__ unsigned short tile[64][72];
    int tid = threadIdx.x;
    int y = blockIdx.y;
    int x0 = blockIdx.x * 64;
    int xl = tid & 63, cq = tid >> 6;  // cq 0..3
#pragma unroll
    for (int ci = 0; ci < 16; ++ci) {
        int c = cq * 16 + ci;
        tile[xl][c] = f2bf(f[c * WH + y * HH + x0 + xl]);
    }
    __syncthreads();
    int cp = tid & 31, xr0 = tid >> 5;  // xr0 0..7
#pragma unroll
    for (int xi = 0; xi < 8; ++xi) {
        int xr = xr0 * 8 + xi;
        unsigned int val = (unsigned int)tile[xr][2 * cp] |
                           ((unsigned int)tile[xr][2 * cp + 1] << 16);
        ((unsigned int*)f_t)[(y * HH + x0 + xr) * 32 + cp] = val;
    }
}

// K2: fused: fp32 offset conv + tanh/cumsum + deform-sample + MFMA conv + GN partials.
// 1-D grid 2304, XCD-chunked decode. Sampling always from f_t[0] (ref quirk).
__global__ __launch_bounds__(256) void k_fused(
    const float* __restrict__ f, const unsigned short* __restrict__ f_t,
    const float* __restrict__ wl_g, const unsigned short* __restrict__ wtA,
    const float* __restrict__ ob, const float* __restrict__ bg,
    const float* __restrict__ bb, const float* __restrict__ cb,
    float* __restrict__ zout, float* __restrict__ pstats)
{
    __shared__ float4 wl4[1728];                // 27.6 KB (offset weights, fp32)
    __shared__ unsigned short def[NT * DEFP];   // 37.4 KB (phase A: partials; phase B: tiles)
    __shared__ short m_y0[KK * NT], m_y1[KK * NT], m_x[KK * NT];
    __shared__ float m_w0[KK * NT], m_w1[KK * NT];
    float* wl = (float*)wl4;
    float* part = (float*)def;                  // [c8][p][9] fp32 partials (9.2 KB)

    int tid = threadIdx.x;
    // XCD-chunked decode: chunk x serves w in [24x, 24x+24)
    int pb = blockIdx.x;
    int xc = pb & 7;
    int j = pb >> 3;                 // 0..287
    int w = xc * 24 + (j % 24);
    int h0 = ((j / 24) % 6) * NT;
    int b = j / 144;

    int lane = tid & 63;
    int wid = tid >> 6;
    int lr = lane & 15;
    int lg = lane >> 4;
    int o0 = wid * 16;

    for (int i = tid; i < 1728; i += 256)
        wl4[i] = ((const float4*)wl_g)[i];

    // ---- phase A: fp32 offset conv, thread = (pixel p, channel-octet c8) ----
    int p = tid & 31, c8 = tid >> 5;
    float acc[9];
#pragma unroll
    for (int jj = 0; jj < 9; ++jj) acc[jj] = 0.f;
    const float* fb = f + ((size_t)b * CIN + c8 * 8) * WH;
    __syncthreads();   // wl ready

#pragma unroll
    for (int tap = 0; tap < 9; ++tap) {
        int r = w + tap / 3 - 1;
        int cl = h0 + p + tap % 3 - 1;
        if ((unsigned)r >= WW || (unsigned)cl >= HH) continue;
        const float* src = fb + r * HH + cl;
#pragma unroll
        for (int cc = 0; cc < 8; ++cc) {
            float v = src[cc * WH];
            const float* ww = wl + (c8 * 8 + cc) * 108 + tap * 12;
            float4 wa = *(const float4*)ww;
            float4 wb2 = *(const float4*)(ww + 4);
            float w8 = ww[8];
            acc[0] += v * wa.x;  acc[1] += v * wa.y;
            acc[2] += v * wa.z;  acc[3] += v * wa.w;
            acc[4] += v * wb2.x; acc[5] += v * wb2.y;
            acc[6] += v * wb2.z; acc[7] += v * wb2.w;
            acc[8] += v * w8;
        }
    }
#pragma unroll
    for (int jj = 0; jj < 9; ++jj)
        part[(c8 * 32 + p) * 9 + jj] = acc[jj];

    // A-fragments for the main conv (overlap load latency with meta phase)
    short8v afr[18];
    const unsigned short* wbase = wtA + (o0 + lr) * 576 + lg * 8;
#pragma unroll
    for (int s = 0; s < 18; ++s)
        afr[s] = *(const short8v*)(wbase + s * 32);
    __syncthreads();

    // ---- reduce partials + tanh + snake-cumsum + sampling meta ----
    if (tid < NT) {
        float s[9];
#pragma unroll
        for (int jj = 0; jj < 9; ++jj) {
            float t0 = 0.f;
#pragma unroll
            for (int g = 0; g < 8; ++g) t0 += part[(g * 32 + tid) * 9 + jj];
            s[jj] = t0;
        }
        const float inv = 1.0f / sqrtf(1.0f + EPSV);
        float t[9];
#pragma unroll
        for (int jj = 0; jj < 9; ++jj)
            t[jj] = tanhf((s[jj] + ob[jj]) * inv * bg[jj] + bb[jj]);
        // cumsum quirk: indices 0 and 8 stay raw (loop is range(1, center))
        float cum[9];
        cum[4] = 0.f;
        cum[5] = t[5]; cum[6] = cum[5] + t[6]; cum[7] = cum[6] + t[7];
        cum[3] = t[3]; cum[2] = cum[3] + t[2]; cum[1] = cum[2] + t[1];
        cum[0] = t[0]; cum[8] = t[8];
        int h = h0 + tid;
#pragma unroll
        for (int k = 0; k < 9; ++k) {
            float yf = cum[k] + (float)w;
            int x = h + k - CENTER;
            float y0f = floorf(yf);
            int iy0 = (int)y0f;
            int y0i = min(max(iy0, 0), WW - 1);
            int y1i = min(max(iy0 + 1, 0), WW - 1);
            float y0w = fminf(fmaxf(y0f, 0.f), (float)WW);
            float y1w = fminf(fmaxf(y0f + 1.f, 0.f), (float)WW);
            float w0 = y1w - yf;
            float w1 = yf - y0w;
            if (x < 0 || x >= HH) { w0 = 0.f; w1 = 0.f; }
            int pp = k * NT + tid;
            m_y0[pp] = (short)y0i;
            m_y1[pp] = (short)y1i;
            m_x[pp]  = (short)min(max(x, 0), HH - 1);
            m_w0[pp] = w0;
            m_w1[pp] = w1;
        }
    }
    __syncthreads();

    // ---- phase B staging: def[hl][k*64+c], bilinear in y from f_t[0] ----
    for (int it = tid; it < KK * NT * 4; it += 256) {
        int q = it & 3;            // channel quarter (16 ch)
        int pp = it >> 2;          // (k,hl) pair
        int y0i = m_y0[pp], y1i = m_y1[pp], x = m_x[pp];
        float w0 = m_w0[pp], w1 = m_w1[pp];
        const unsigned short* r0 = f_t + ((y0i * HH + x) << 6) + q * 16;
        const unsigned short* r1 = f_t + ((y1i * HH + x) << 6) + q * 16;
        short8v a0 = *(const short8v*)r0;
        short8v a1 = *(const short8v*)(r0 + 8);
        short8v c0 = *(const short8v*)r1;
        short8v c1 = *(const short8v*)(r1 + 8);
        short8v o0v, o1v;
#pragma unroll
        for (int c = 0; c < 8; ++c) {
            float v0 = bf2f((unsigned short)a0[c]) * w0 + bf2f((unsigned short)c0[c]) * w1;
            float v1 = bf2f((unsigned short)a1[c]) * w0 + bf2f((unsigned short)c1[c]) * w1;
            o0v[c] = (short)f2bf(v0);
            o1v[c] = (short)f2bf(v1);
        }
        int hl = pp & 31;
        int k = pp >> 5;
        unsigned short* d = &def[hl * DEFP + k * 64 + q * 16];
        *(short8v*)d = o0v;
        *(short8v*)(d + 8) = o1v;
    }
    __syncthreads();

    // ---- phase B MFMA: C[16o x 32h] per wave, K=576 in 18 steps ----
    float4v acc0 = {0.f, 0.f, 0.f, 0.f};
    float4v acc1 = {0.f, 0.f, 0.f, 0.f};
    const unsigned short* drow0 = &def[lr * DEFP + lg * 8];
    const unsigned short* drow1 = &def[(16 + lr) * DEFP + lg * 8];
#pragma unroll
    for (int s = 0; s < 18; ++s) {
        short8v b0 = *(const short8v*)(drow0 + s * 32);
        short8v b1 = *(const short8v*)(drow1 + s * 32);
        acc0 = __builtin_amdgcn_mfma_f32_16x16x32_bf16(afr[s], b0, acc0, 0, 0, 0);
        acc1 = __builtin_amdgcn_mfma_f32_16x16x32_bf16(afr[s], b1, acc1, 0, 0, 0);
    }

    // epilogue: bias + store z + GN partial stats (no atomics)
    float4 cbv = *(const float4*)(cb + o0 + lg * 4);
    float lsum = 0.f, lsq = 0.f;
    size_t base = ((size_t)(b * COUT + o0 + lg * 4) * WW + w) * HH + h0 + lr;
#pragma unroll
    for (int r = 0; r < 4; ++r) {
        float bias = (r == 0) ? cbv.x : (r == 1) ? cbv.y : (r == 2) ? cbv.z : cbv.w;
        float z0 = acc0[r] + bias;
        float z1 = acc1[r] + bias;
        zout[base + (size_t)r * WH]      = z0;
        zout[base + (size_t)r * WH + 16] = z1;
        lsum += z0 + z1;
        lsq  += z0 * z0 + z1 * z1;
    }
#pragma unroll
    for (int m = 1; m < 16; m <<= 1) {
        lsum += __shfl_xor(lsum, m);
        lsq  += __shfl_xor(lsq, m);
    }
    if (lr == 0) {
        int g = wid * 4 + lg;                 // GN group of this lane's 4 channels
        pstats[(size_t)pb * 32 + g]      = lsum;
        pstats[(size_t)pb * 32 + 16 + g] = lsq;
    }
}

// K3: reduce per-block partials -> mean/istd. 32 blocks (b,g).
__global__ __launch_bounds__(1024) void k_stats2(const float* __restrict__ pstats,
                                                 float* __restrict__ ms)
{
    __shared__ float sL[16], qL[16];
    int b = blockIdx.x >> 4, g = blockIdx.x & 15;
    float s = 0.f, q = 0.f;
    for (int pb = threadIdx.x; pb < NBLK; pb += 1024) {
        int bb = (pb >> 3) / 144;
        if (bb == b) {
            s += pstats[(size_t)pb * 32 + g];
            q += pstats[(size_t)pb * 32 + 16 + g];
        }
    }
#pragma unroll
    for (int m = 1; m < 64; m <<= 1) {
        s += __shfl_xor(s, m);
        q += __shfl_xor(q, m);
    }
    int wv = threadIdx.x >> 6;
    if ((threadIdx.x & 63) == 0) { sL[wv] = s; qL[wv] = q; }
    __syncthreads();
    if (threadIdx.x == 0) {
        float ts = 0.f, tq = 0.f;
#pragma unroll
        for (int i = 0; i < 16; ++i) { ts += sL[i]; tq += qL[i]; }
        float mean = ts / (float)NPERG;
        float var = tq / (float)NPERG - mean * mean;
        ms[b * GROUPS + g] = mean;
        ms[BB * GROUPS + b * GROUPS + g] = 1.0f / sqrtf(var + EPSV);
    }
}

// K4: normalize + affine + relu, in place on d_out
__global__ __launch_bounds__(256) void k_norm(
    float* __restrict__ z, const float* __restrict__ ms,
    const float* __restrict__ gg, const float* __restrict__ gb)
{
    int i = blockIdx.x * 256 + threadIdx.x;
    const int total4 = BB * COUT * WH / 4;
    if (i >= total4) return;
    float4 v = ((float4*)z)[i];
    int idx = i * 4;
    int o = (idx / WH) % COUT;
    int b = idx / (COUT * WH);
    int g = o >> 2;
    float mean = ms[b * GROUPS + g];
    float istd = ms[BB * GROUPS + b * GROUPS + g];
    float ga = gg[o], be = gb[o];
    v.x = fmaxf((v.x - mean) * istd * ga + be, 0.f);
    v.y = fmaxf((v.y - mean) * istd * ga + be, 0.f);
    v.z = fmaxf((v.z - mean) * istd * ga + be, 0.f);
    v.w = fmaxf((v.w - mean) * istd * ga + be, 0.f);
    ((float4*)z)[i] = v;
}

extern "C" void kernel_launch(void* const* d_in, const int* in_sizes, int n_in,
                              void* d_out, int out_size, void* d_ws, size_t ws_size,
                              hipStream_t stream)
{
    const float* f  = (const float*)d_in[0];
    const float* ow = (const float*)d_in[1];
    const float* ob = (const float*)d_in[2];
    const float* bg = (const float*)d_in[3];
    const float* bb = (const float*)d_in[4];
    const float* cw = (const float*)d_in[5];
    const float* cb = (const float*)d_in[6];
    const float* gg = (const float*)d_in[7];
    const float* gb = (const float*)d_in[8];
    float* out = (float*)d_out;

    char* ws = (char*)d_ws;
    unsigned short* f_t = (unsigned short*)ws;                      // 4,718,592 B
    unsigned short* wtA = (unsigned short*)(ws + 4718592);          // 73,728 B
    float* wl_g         = (float*)(ws + 4718592 + 73728);           // 27,648 B
    float* pstats       = (float*)(ws + 4718592 + 73728 + 27648);   // 294,912 B
    float* ms           = (float*)(ws + 4718592 + 73728 + 27648 + 294912); // 256 B

    k_prep<<<(36864 + 6912 + 255) / 256, 256, 0, stream>>>(cw, ow, wtA, wl_g);
    k_tr<<<dim3(3, WW), 256, 0, stream>>>(f, f_t);
    k_fused<<<NBLK, 256, 0, stream>>>(f, f_t, wl_g, wtA, ob, bg, bb, cb, out, pstats);
    k_stats2<<<BB * GROUPS, 1024, 0, stream>>>(pstats, ms);
    k_norm<<<(BB * COUT * WH / 4 + 255) / 256, 256, 0, stream>>>(out, ms, gg, gb);
}